// Round 13
// baseline (457.701 us; speedup 1.0000x reference)
//
#include <hip/hip_runtime.h>
#include <hip/hip_fp16.h>

// N=50000 nodes, E=850000 edges, H=8 heads, D=32, H*D=256, IN=128, SM=256, SP=128

typedef unsigned int uint32;
typedef unsigned short u16;
typedef float f32x4 __attribute__((ext_vector_type(4)));
typedef _Float16 f16x2 __attribute__((ext_vector_type(2)));
typedef _Float16 f16x4 __attribute__((ext_vector_type(4)));
typedef _Float16 f16x8 __attribute__((ext_vector_type(8)));

union H2 { f16x2 v; uint32 u; };

__device__ __forceinline__ int wave_incl_scan(int x) {
  int lane = threadIdx.x & 63;
#pragma unroll
  for (int off = 1; off < 64; off <<= 1) {
    int t = __shfl_up(x, off, 64);
    if (lane >= off) x += t;
  }
  return x;
}

// single-block chunked exclusive scan of deg[0..n) -> rp; rp[n]=Etot. 1024 threads.
__global__ __launch_bounds__(1024) void k_scan1(const int* __restrict__ deg, int* __restrict__ rp,
                                                int n, int Etot) {
  __shared__ int wpart[16];
  __shared__ int sbase;
  int tid = threadIdx.x, lane = tid & 63, wid = tid >> 6;
  if (tid == 0) sbase = 0;
  __syncthreads();
  for (int c0 = 0; c0 < n; c0 += 4096) {
    int i0 = c0 + tid * 4;
    int v0 = 0, v1 = 0, v2 = 0, v3 = 0;
    if (i0 + 3 < n) {
      int4 t = *(const int4*)(deg + i0);
      v0 = t.x; v1 = t.y; v2 = t.z; v3 = t.w;
    } else {
      if (i0 < n) v0 = deg[i0];
      if (i0 + 1 < n) v1 = deg[i0 + 1];
      if (i0 + 2 < n) v2 = deg[i0 + 2];
      if (i0 + 3 < n) v3 = deg[i0 + 3];
    }
    int ts = v0 + v1 + v2 + v3;
    int incl = wave_incl_scan(ts);
    if (lane == 63) wpart[wid] = incl;
    __syncthreads();
    if (wid == 0 && lane < 16) {
      int xv = wpart[lane];
#pragma unroll
      for (int off = 1; off < 16; off <<= 1) {
        int t = __shfl_up(xv, off, 64);
        if (lane >= off) xv += t;
      }
      wpart[lane] = xv;  // inclusive over wave partials
    }
    __syncthreads();
    int tot = wpart[15];  // read into register BEFORE the next chunk overwrites wpart
    int base = sbase + (wid ? wpart[wid - 1] : 0);
    int excl = base + incl - ts;
    if (i0 + 3 < n) {
      int4 o; o.x = excl; o.y = excl + v0; o.z = excl + v0 + v1; o.w = excl + v0 + v1 + v2;
      *(int4*)(rp + i0) = o;
    } else {
      if (i0 < n) rp[i0] = excl;
      if (i0 + 1 < n) rp[i0 + 1] = excl + v0;
      if (i0 + 2 < n) rp[i0 + 2] = excl + v0 + v1;
      if (i0 + 3 < n) rp[i0 + 3] = excl + v0 + v1 + v2;
    }
    __syncthreads();  // all reads of sbase/wpart done before tid0 mutates sbase
    if (tid == 0) sbase += tot;
  }
  if (tid == 0) rp[n] = Etot;
}

// ---- merged: layer-1 weight fold (blocks [0,770)) + degree count (blocks [770,..)) ----
__global__ __launch_bounds__(256) void k_predeg(const float* __restrict__ T1w, const float* __restrict__ T1b,
                                                const float* __restrict__ T2w, const float* __restrict__ T2b,
                                                const float* __restrict__ G1, const float* __restrict__ G2,
                                                __half* __restrict__ Bf, float* __restrict__ cvec,
                                                const int* __restrict__ dst, int* __restrict__ deg, int E) {
  int bb = blockIdx.x;
  int j = threadIdx.x;
  if (bb >= 770) {  // degree-count branch (block-uniform)
    int e = (bb - 770) * 256 + j;
    if (e < E) atomicAdd(&deg[dst[e]], 1);
    return;
  }
  const float* G = (bb < 385) ? G1 : G2;
  int off = (bb < 385) ? 0 : 256;
  int r = (bb < 385) ? bb : bb - 385;  // 0..384: K index (384 rows) + 1 bias row
  float acc = 0.f;
  if (r < 256) {
    for (int m = 0; m < 128; m++) acc += T1w[r * 128 + m] * G[m * 256 + j];
  } else if (r < 384) {
    int rr = r - 256;
    for (int m = 0; m < 128; m++) acc += T2w[rr * 128 + m] * G[(128 + m) * 256 + j];
  } else {
    for (int m = 0; m < 128; m++) acc += T1b[m] * G[m * 256 + j] + T2b[m] * G[(128 + m) * 256 + j];
    cvec[off + j] = acc;
    return;
  }
  int k = r, colabs = off + j;
  int kt = k >> 5, lq = (k >> 3) & 3, j8 = k & 7;
  int cb = colabs >> 7, colr = colabs & 127, ni = colr >> 4, lr = colr & 15;
  size_t idx = ((size_t)(((cb * 12 + kt) * 8 + ni) * 4 + lq) * 16 + lr) * 8 + j8;
  Bf[idx] = __float2half(acc);
}

// async global->LDS, 16B per lane; LDS dest is wave-uniform base + lane*16
#define GLL(GP, LP)                                                     \
  __builtin_amdgcn_global_load_lds(                                     \
      (const __attribute__((address_space(1))) void*)(GP),              \
      (__attribute__((address_space(3))) void*)(LP), 16, 0, 0)

// ---- merged: fp16 MFMA GEMM (blocks [0,GB)) + CSR fill (blocks [GB,..)) ----
// GEMM (proven v9/v12 pipeline) with HEAD-SLICED output [head][N][32] fp16 so the layer-1
// edge pass gathers from per-XCD L2-resident slices.
__global__ __launch_bounds__(256, 4) void k_gemmfill(const float* __restrict__ sm, const float* __restrict__ sp,
                                                     const u16* __restrict__ Bf, const float* __restrict__ cvec,
                                                     __half* __restrict__ fs, __half* __restrict__ fd, int N,
                                                     int GB, const int* __restrict__ src,
                                                     const int* __restrict__ dst, const int* __restrict__ rp,
                                                     int* __restrict__ cnt, int* __restrict__ csr_src, int E) {
  __shared__ u16 BFl[3 * 4096];  // 24 KB: B fragments, identity-mapped GLL
  __shared__ u16 AFl[2 * 4096];  // 16 KB: A fp16 [slot][128 rows][32 halves], XOR-swizzled
  int tid = threadIdx.x;
  if (blockIdx.x >= GB) {  // CSR-fill branch (block-uniform; no barriers touched)
    int e = (blockIdx.x - GB) * 256 + tid;
    if (e < E) {
      int d = dst[e];
      int p = rp[d] + atomicAdd(&cnt[d], 1);
      csr_src[p] = src[e];
    }
    return;
  }
  int w = tid >> 6, l = tid & 63;
  int lr = l & 15, lq = l >> 4;
  int L = blockIdx.x;
  int x = L & 7, m = L >> 3;
  int cb = m & 3;
  int rb = x + 8 * (m >> 2);
  int col0 = cb * 128, row0 = rb * 128;
  if (row0 >= N) return;  // padded row-panels: whole block exits uniformly (before barriers)

  int o_sm[4], o_sp[4], woff[4];
#pragma unroll
  for (int i = 0; i < 4; i++) {
    int idx = i * 256 + tid;
    int r = idx >> 3, c8 = idx & 7;
    int rg = row0 + r; if (rg >= N) rg = N - 1;
    o_sm[i] = rg * 256 + c8 * 4;  // float units
    o_sp[i] = rg * 128 + c8 * 4;
    woff[i] = r * 32 + ((c8 * 4) ^ ((r & 6) << 2));  // halfword units, XOR-swizzled
  }
  int r0l = w * 32 + lr, r1l = r0l + 16;
  int ra0 = r0l * 32 + ((lq * 8) ^ ((r0l & 6) << 2));
  int ra1 = r1l * 32 + ((lq * 8) ^ ((r1l & 6) << 2));

  f32x4 acc[2][8];
#pragma unroll
  for (int mt = 0; mt < 2; mt++)
#pragma unroll
    for (int ni = 0; ni < 8; ni++) acc[mt][ni] = (f32x4){0.f, 0.f, 0.f, 0.f};

#define STAGE_B(S, BUF)                                                 \
  {                                                                     \
    size_t g0 = (size_t)(cb * 12 + (S)) * 4096;                         \
    _Pragma("unroll") for (int i = 0; i < 2; i++) {                     \
      int c = i * 256 + tid;                                            \
      int lb = (BUF)*4096 + (i * 4 + w) * 512;                          \
      GLL(Bf + g0 + (size_t)c * 8, &BFl[lb]);                           \
    }                                                                   \
  }

#define ALOAD(S)                                                        \
  {                                                                     \
    _Pragma("unroll") for (int i = 0; i < 4; i++) {                     \
      const float* g = ((S) < 8) ? (sm + o_sm[i] + (S)*32) : (sp + o_sp[i] + ((S)-8) * 32); \
      D[i] = *(const float4*)g;                                         \
    }                                                                   \
  }

#define AWRITE(SLOT)                                                    \
  {                                                                     \
    _Pragma("unroll") for (int i = 0; i < 4; i++) {                     \
      f16x4 h;                                                          \
      h[0] = (_Float16)D[i].x; h[1] = (_Float16)D[i].y;                 \
      h[2] = (_Float16)D[i].z; h[3] = (_Float16)D[i].w;                 \
      *(f16x4*)&AFl[(SLOT)*4096 + woff[i]] = h;                         \
    }                                                                   \
  }

  float4 D[4];
  ALOAD(0);         // [A0:4]
  STAGE_B(0, 0);    // [G0:2]
  STAGE_B(1, 1);    // [G1:2] -> outstanding 8
  asm volatile("s_waitcnt vmcnt(4)" ::: "memory");  // A0 done (G0,G1 in flight)
  AWRITE(0);
  asm volatile("s_waitcnt vmcnt(2)" ::: "memory");  // G0 done (G1 in flight)
  asm volatile("s_waitcnt lgkmcnt(0)" ::: "memory");  // drain AWRITE before barrier
  __builtin_amdgcn_sched_barrier(0);
  __builtin_amdgcn_s_barrier();

#pragma unroll
  for (int st = 0; st < 12; st++) {
    const int cu = st & 1, nx = cu ^ 1, bs = st % 3;
    if (st < 11) ALOAD(st + 1);                  // A(st+1): covered by this stage's compute
    if (st < 10) STAGE_B(st + 2, (st + 2) % 3);  // G(st+2): in flight across next barrier
    f16x8 a0 = *(const f16x8*)&AFl[cu * 4096 + ra0];
    f16x8 a1 = *(const f16x8*)&AFl[cu * 4096 + ra1];
#pragma unroll
    for (int ni = 0; ni < 8; ni++) {
      f16x8 bf = *(const f16x8*)&BFl[bs * 4096 + (ni * 64 + l) * 8];  // lane-contiguous
      acc[0][ni] = __builtin_amdgcn_mfma_f32_16x16x32_f16(a0, bf, acc[0][ni], 0, 0, 0);
      acc[1][ni] = __builtin_amdgcn_mfma_f32_16x16x32_f16(a1, bf, acc[1][ni], 0, 0, 0);
    }
    if (st < 10) {
      asm volatile("s_waitcnt vmcnt(2)" ::: "memory");
    } else if (st == 10) {
      asm volatile("s_waitcnt vmcnt(0)" ::: "memory");
    }
    if (st < 11) {
      AWRITE(nx);
      asm volatile("s_waitcnt lgkmcnt(0)" ::: "memory");  // drain ds_writes before barrier
      __builtin_amdgcn_sched_barrier(0);
      __builtin_amdgcn_s_barrier();
    }
  }

  // epilogue: head-sliced store: element (head, node, feat) at [(head*N + node)*32 + feat]
#pragma unroll
  for (int mt = 0; mt < 2; mt++) {
    int rbr = row0 + w * 32 + mt * 16 + lq * 4;
#pragma unroll
    for (int ni = 0; ni < 8; ni++) {
      int c = col0 + ni * 16 + lr;
      float cv = cvec[c];
      __half* op = fs; int cc = c;
      if (c >= 256) { op = fd; cc = c - 256; }
      int hh = cc >> 5, ff = cc & 31;
#pragma unroll
      for (int r = 0; r < 4; r++) {
        int rr = rbr + r;
        if (rr < N) op[((size_t)hh * N + rr) * 32 + ff] = __float2half(acc[mt][ni][r] + cv);
      }
    }
  }
#undef STAGE_B
#undef ALOAD
#undef AWRITE
}

// ---- layer-1 head-sliced edge pass v13: wave = 16 dst-tasks x 4 feat-lanes, one head ----
// h = blockIdx%8 -> XCD-routed, 3.2MB head slice L2-resident. Each task walks its dst's
// FULL edge list serially (fixed cost amortized over ~17-26 iters; __any exit). acc stays
// lane-local (zero epilogue shuffles); den quad-uniform from the 2 in-loop shuffles.
// fp16 partial written IN-PLACE over fd[h][n] (read-once-then-write, v11-proven).
// Prologue loads / epilogue stores: 16 consecutive rows = contiguous 1KB per wave.
__global__ __launch_bounds__(256) void k_edge1s(const u16* __restrict__ fsh, u16* fdh,
                                                const int* __restrict__ csr_src, const int* __restrict__ rp,
                                                const float* __restrict__ attn, const float* __restrict__ bias,
                                                int N) {
  int B = blockIdx.x;
  int h = B & 7, g = B >> 3;
  int lane = threadIdx.x & 63, wid = threadIdx.x >> 6;
  int t = lane >> 2, q = lane & 3;
  int nr = g * 64 + wid * 16 + t;
  bool valid = nr < N;
  int n = valid ? nr : N - 1;
  int fo = q * 8;
  size_t sb = (size_t)h * N * 32;
  size_t nb = sb + (size_t)n * 32 + fo;
  uint4 yu = *(const uint4*)&fdh[nb];
  H2 Y0, Y1, Y2, Y3;
  Y0.u = yu.x; Y1.u = yu.y; Y2.u = yu.z; Y3.u = yu.w;
  const float* ap = attn + h * 32 + fo;
  float4 a0 = *(const float4*)ap;
  float4 a1 = *(const float4*)(ap + 4);
  H2 A0, A1, A2, A3;
  A0.v = (f16x2){(_Float16)a0.x, (_Float16)a0.y};
  A1.v = (f16x2){(_Float16)a0.z, (_Float16)a0.w};
  A2.v = (f16x2){(_Float16)a1.x, (_Float16)a1.y};
  A3.v = (f16x2){(_Float16)a1.z, (_Float16)a1.w};
  const f16x2 c02 = {(_Float16)0.2f, (_Float16)0.2f};
  int beg = rp[n], end = rp[n + 1];
  float den = 0.f;
  float acc[8] = {0.f, 0.f, 0.f, 0.f, 0.f, 0.f, 0.f, 0.f};

  for (int i = 0; __any(beg + i < end); i++) {
    int ei = beg + i;
    bool ve = ei < end;
    int s = csr_src[ve ? ei : beg];
    uint4 xu = *(const uint4*)&fsh[sb + (size_t)s * 32 + fo];
    H2 X0, X1, X2, X3;
    X0.u = xu.x; X1.u = xu.y; X2.u = xu.z; X3.u = xu.w;
    f16x2 e0 = X0.v + Y0.v, e1 = X1.v + Y1.v, e2 = X2.v + Y2.v, e3 = X3.v + Y3.v;
    f16x2 t0 = __builtin_elementwise_max(e0, e0 * c02);
    f16x2 t1 = __builtin_elementwise_max(e1, e1 * c02);
    f16x2 t2 = __builtin_elementwise_max(e2, e2 * c02);
    f16x2 t3 = __builtin_elementwise_max(e3, e3 * c02);
    float p = __builtin_amdgcn_fdot2(t0, A0.v, 0.f, false);
    p = __builtin_amdgcn_fdot2(t1, A1.v, p, false);
    p = __builtin_amdgcn_fdot2(t2, A2.v, p, false);
    p = __builtin_amdgcn_fdot2(t3, A3.v, p, false);
    p += __shfl_xor(p, 1, 64);  // reduce over the 4 feat-lanes of this task
    p += __shfl_xor(p, 2, 64);
    float wgt = ve ? __expf(p) : 0.f;  // scores bounded: exp-safe without max shift
    den += wgt;
    acc[0] += wgt * (float)X0.v.x; acc[1] += wgt * (float)X0.v.y;
    acc[2] += wgt * (float)X1.v.x; acc[3] += wgt * (float)X1.v.y;
    acc[4] += wgt * (float)X2.v.x; acc[5] += wgt * (float)X2.v.y;
    acc[6] += wgt * (float)X3.v.x; acc[7] += wgt * (float)X3.v.y;
  }
  float invd = 1.f / den;
  const float* bp = bias + h * 32 + fo;
  float4 b0 = *(const float4*)bp;
  float4 b1 = *(const float4*)(bp + 4);
  float bj[8] = {b0.x, b0.y, b0.z, b0.w, b1.x, b1.y, b1.z, b1.w};
  float v[8];
#pragma unroll
  for (int j = 0; j < 8; j++) {
    float tv = acc[j] * invd + bj[j];
    v[j] = tv > 0.f ? tv : expm1f(tv);  // elu (layer 1)
  }
  if (valid) {  // in-place fp16 partial over fd[h][n] (this task's own row)
    H2 P0, P1, P2, P3;
    P0.v = (f16x2){(_Float16)v[0], (_Float16)v[1]};
    P1.v = (f16x2){(_Float16)v[2], (_Float16)v[3]};
    P2.v = (f16x2){(_Float16)v[4], (_Float16)v[5]};
    P3.v = (f16x2){(_Float16)v[6], (_Float16)v[7]};
    uint4 st = {P0.u, P1.u, P2.u, P3.u};
    *(uint4*)&fdh[nb] = st;
  }
}

// ---- head combine: hmid[n][f] = (1/8) sum_h part[h][n][f] (fp16 partials, v11-proven) ----
__global__ __launch_bounds__(256) void k_comb16(const u16* __restrict__ p, float* __restrict__ o, int N) {
  int idx = blockIdx.x * 256 + threadIdx.x;
  if (idx >= N * 8) return;  // N*32/4 groups
  size_t base = (size_t)idx * 4;
  size_t stride = (size_t)N * 32;
  float s0 = 0.f, s1 = 0.f, s2 = 0.f, s3 = 0.f;
#pragma unroll
  for (int h = 0; h < 8; h++) {
    uint2 u = *(const uint2*)&p[h * stride + base];
    H2 a, b; a.u = u.x; b.u = u.y;
    s0 += (float)a.v.x; s1 += (float)a.v.y; s2 += (float)b.v.x; s3 += (float)b.v.y;
  }
  float4 r = {s0 * 0.125f, s1 * 0.125f, s2 * 0.125f, s3 * 0.125f};
  *(float4*)&o[base] = r;
}

// ---- layer-2 feature GEMM: fs/fd[N,256] = h[N,32] @ W[32,256], interleaved fp16 ----
__global__ __launch_bounds__(256) void k_feat2(const float* __restrict__ h, const float* __restrict__ Ws,
                                               const float* __restrict__ Wd, __half* __restrict__ fs,
                                               __half* __restrict__ fd, int N) {
  int j = threadIdx.x;
  int n0 = blockIdx.x * 32;
  float ws[32], wd[32];
#pragma unroll
  for (int k = 0; k < 32; k++) {
    ws[k] = Ws[k * 256 + j];
    wd[k] = Wd[k * 256 + j];
  }
  int nend = n0 + 32; if (nend > N) nend = N;
#pragma unroll 2
  for (int n = n0; n < nend; n++) {
    const float4* hr4 = (const float4*)(h + (size_t)n * 32);  // wave-uniform -> s_load_dwordx4
    float as = 0.f, ad = 0.f;
#pragma unroll
    for (int kk = 0; kk < 8; kk++) {
      float4 t = hr4[kk];
      as += t.x * ws[4 * kk] + t.y * ws[4 * kk + 1] + t.z * ws[4 * kk + 2] + t.w * ws[4 * kk + 3];
      ad += t.x * wd[4 * kk] + t.y * wd[4 * kk + 1] + t.z * wd[4 * kk + 2] + t.w * wd[4 * kk + 3];
    }
    fs[(size_t)n * 256 + j] = __float2half(as);
    fd[(size_t)n * 256 + j] = __float2half(ad);
  }
}

// ---- layer-2 edge pass: half-wave edge pairing (proven r6), interleaved layout ----
__global__ __launch_bounds__(256) void k_edge2(const uint4* __restrict__ fs4, const uint4* __restrict__ fd4,
                                               const int* __restrict__ csr_src, const int* __restrict__ rp,
                                               const float* __restrict__ attn, const float* __restrict__ bias,
                                               float* __restrict__ out, int N) {
  int n = blockIdx.x * 4 + (threadIdx.x >> 6);
  if (n >= N) return;
  int lane = threadIdx.x & 63;
  int lh = lane & 31;  // position within half; lane holds feats 8*lh .. 8*lh+7
  float4 a0 = ((const float4*)attn)[lh * 2];
  float4 a1 = ((const float4*)attn)[lh * 2 + 1];
  H2 AV01, AV23, AV45, AV67;
  AV01.v = (f16x2){(_Float16)a0.x, (_Float16)a0.y};
  AV23.v = (f16x2){(_Float16)a0.z, (_Float16)a0.w};
  AV45.v = (f16x2){(_Float16)a1.x, (_Float16)a1.y};
  AV67.v = (f16x2){(_Float16)a1.z, (_Float16)a1.w};
  const f16x2 c02 = {(_Float16)0.2f, (_Float16)0.2f};
  uint4 yu = fd4[(size_t)n * 32 + lh];
  H2 Y01, Y23, Y45, Y67;
  Y01.u = yu.x; Y23.u = yu.y; Y45.u = yu.z; Y67.u = yu.w;
  int beg = rp[n], end = rp[n + 1];
  float den = 0.f;
  float acc[8] = {0.f, 0.f, 0.f, 0.f, 0.f, 0.f, 0.f, 0.f};

  auto pair1 = [&](uint4 xu, bool tail) {
    H2 Xa, Xb, Xc, Xd;
    Xa.u = xu.x; Xb.u = xu.y; Xc.u = xu.z; Xd.u = xu.w;
    f16x2 e0 = Xa.v + Y01.v, e1 = Xb.v + Y23.v, e2 = Xc.v + Y45.v, e3 = Xd.v + Y67.v;
    f16x2 t0 = __builtin_elementwise_max(e0, e0 * c02);
    f16x2 t1 = __builtin_elementwise_max(e1, e1 * c02);
    f16x2 t2 = __builtin_elementwise_max(e2, e2 * c02);
    f16x2 t3 = __builtin_elementwise_max(e3, e3 * c02);
    float p = __builtin_amdgcn_fdot2(t0, AV01.v, 0.f, false);
    p = __builtin_amdgcn_fdot2(t1, AV23.v, p, false);
    p = __builtin_amdgcn_fdot2(t2, AV45.v, p, false);
    p = __builtin_amdgcn_fdot2(t3, AV67.v, p, false);
    p += __shfl_xor(p, 1, 64);  // 4-lane head group reduce
    p += __shfl_xor(p, 2, 64);
    float wgt = __expf(p);  // scores bounded: exp-safe without max shift
    if (tail && lane >= 32) wgt = 0.f;  // odd-degree tail: half B invalid
    den += wgt;
    acc[0] += wgt * (float)Xa.v.x; acc[1] += wgt * (float)Xa.v.y;
    acc[2] += wgt * (float)Xb.v.x; acc[3] += wgt * (float)Xb.v.y;
    acc[4] += wgt * (float)Xc.v.x; acc[5] += wgt * (float)Xc.v.y;
    acc[6] += wgt * (float)Xd.v.x; acc[7] += wgt * (float)Xd.v.y;
  };

  int e = beg;
  int np = (end - beg) >> 1;
  if (np > 0) {
    int sA = csr_src[e], sB = csr_src[e + 1];  // wave-uniform scalar loads
    int s = (lane < 32) ? sA : sB;
    uint4 xcur = fs4[(size_t)s * 32 + lh];
    for (int q = 1; q < np; q++) {
      int eb = e + 2 * q;
      int tA = csr_src[eb], tB = csr_src[eb + 1];
      int t = (lane < 32) ? tA : tB;
      uint4 xnext = fs4[(size_t)t * 32 + lh];  // prefetch next pair
      pair1(xcur, false);
      xcur = xnext;
    }
    pair1(xcur, false);
    e += 2 * np;
  }
  if (e < end) {  // odd-degree tail
    int sA = csr_src[e];
    uint4 xu = fs4[(size_t)sA * 32 + lh];
    pair1(xu, true);
  }

  // cross-half combine: halves A/B accumulated disjoint edge subsets of the same dst
  den += __shfl_xor(den, 32, 64);
#pragma unroll
  for (int j = 0; j < 8; j++) acc[j] += __shfl_xor(acc[j], 32, 64);
  float invd = 1.f / den;
  float4 b0 = ((const float4*)bias)[lh * 2];
  float4 b1 = ((const float4*)bias)[lh * 2 + 1];
  float bj[8] = {b0.x, b0.y, b0.z, b0.w, b1.x, b1.y, b1.z, b1.w};
#pragma unroll
  for (int j = 0; j < 8; j++) acc[j] = acc[j] * invd + bj[j];
  // head-mean: feat f = lh*8+j; head h = lh>>2; d = (lh&3)*8+j -> reduce lanes stride-4
#pragma unroll
  for (int mask = 4; mask <= 16; mask <<= 1)
#pragma unroll
    for (int j = 0; j < 8; j++) acc[j] += __shfl_xor(acc[j], mask, 64);
  if (lane < 4) {  // lane p holds d = p*8 .. p*8+7
    float4 o0 = {acc[0] * 0.125f, acc[1] * 0.125f, acc[2] * 0.125f, acc[3] * 0.125f};
    float4 o1 = {acc[4] * 0.125f, acc[5] * 0.125f, acc[6] * 0.125f, acc[7] * 0.125f};
    ((float4*)out)[(size_t)n * 8 + lane * 2] = o0;
    ((float4*)out)[(size_t)n * 8 + lane * 2 + 1] = o1;
  }
}

extern "C" void kernel_launch(void* const* d_in, const int* in_sizes, int n_in,
                              void* d_out, int out_size, void* d_ws, size_t ws_size,
                              hipStream_t stream) {
  const float* sm  = (const float*)d_in[0];
  const float* sp  = (const float*)d_in[1];
  const int*   src = (const int*)d_in[2];
  const int*   dst = (const int*)d_in[3];
  const float* T1w = (const float*)d_in[4];
  const float* T1b = (const float*)d_in[5];
  const float* T2w = (const float*)d_in[6];
  const float* T2b = (const float*)d_in[7];
  const float* g1sw = (const float*)d_in[8];
  const float* g1dw = (const float*)d_in[9];
  const float* g1a  = (const float*)d_in[10];
  const float* g1b  = (const float*)d_in[11];
  const float* g2sw = (const float*)d_in[12];
  const float* g2dw = (const float*)d_in[13];
  const float* g2a  = (const float*)d_in[14];
  const float* g2b  = (const float*)d_in[15];
  const int N = in_sizes[1] / 128;  // sp_feats is [N,128]
  const int E = in_sizes[2];
  float* out = (float*)d_out;

  size_t off = 0;
  char* wsb = (char*)d_ws;
  auto alloc = [&](size_t bytes) -> void* {
    void* p = wsb + off;
    off += (bytes + 255) & ~(size_t)255;
    return p;
  };
  __half* Bf  = (__half*)alloc((size_t)512 * 384 * 2);
  float* cvec  = (float*)alloc(512 * 4);
  int* deg     = (int*)alloc((size_t)N * 4);
  int* cnt     = (int*)alloc((size_t)N * 4);
  int* row_ptr = (int*)alloc((size_t)(N + 1) * 4);
  int* csr_src = (int*)alloc((size_t)E * 4);
  __half* fs   = (__half*)alloc((size_t)N * 256 * 2);
  __half* fd   = (__half*)alloc((size_t)N * 256 * 2);
  float* hmid  = (float*)alloc((size_t)N * 32 * 4);
  (void)ws_size; (void)n_in; (void)out_size;

  (void)hipMemsetAsync(deg, 0, (size_t)N * 4, stream);
  (void)hipMemsetAsync(cnt, 0, (size_t)N * 4, stream);

  int DB = (E + 255) / 256;  // edge blocks

  // merged: precomb (770 blocks) || degree count (DB blocks)
  k_predeg<<<770 + DB, 256, 0, stream>>>(T1w, T1b, T2w, T2b, g1sw, g1dw, Bf, cvec, dst, deg, E);
  k_scan1<<<1, 1024, 0, stream>>>(deg, row_ptr, N, E);

  // merged: layer-1 GEMM (GB blocks, head-sliced out, XCD-swizzled) || CSR fill (DB blocks)
  int rbs = (N + 127) / 128;
  int rbp = (rbs + 7) & ~7;
  int GB = rbp * 4;
  k_gemmfill<<<GB + DB, 256, 0, stream>>>(sm, sp, (const u16*)Bf, cvec, fs, fd, N,
                                          GB, src, dst, row_ptr, cnt, csr_src, E);

  // layer 1: head-sliced edge pass (16 tasks x 4 lanes per wave), in-place partials, combine
  int e1grid = ((N + 63) / 64) * 8;
  k_edge1s<<<e1grid, 256, 0, stream>>>((const u16*)fs, (u16*)fd, csr_src, row_ptr, g1a, g1b, N);
  k_comb16<<<(N * 8 + 255) / 256, 256, 0, stream>>>((const u16*)fd, hmid, N);

  // layer 2: interleaved layout + proven half-wave edge kernel
  k_feat2<<<(N + 31) / 32, 256, 0, stream>>>(hmid, g2sw, g2dw, fs, fd, N);
  k_edge2<<<(N + 3) / 4, 256, 0, stream>>>((const uint4*)fs, (const uint4*)fd, csr_src, row_ptr, g2a, g2b, out, N);
}

// Round 14
// 444.641 us; speedup vs baseline: 1.0294x; 1.0294x over previous
//
#include <hip/hip_runtime.h>
#include <hip/hip_fp16.h>

// N=50000 nodes, E=850000 edges, H=8 heads, D=32, H*D=256, IN=128, SM=256, SP=128

typedef unsigned int uint32;
typedef unsigned short u16;
typedef float f32x4 __attribute__((ext_vector_type(4)));
typedef _Float16 f16x2 __attribute__((ext_vector_type(2)));
typedef _Float16 f16x4 __attribute__((ext_vector_type(4)));
typedef _Float16 f16x8 __attribute__((ext_vector_type(8)));

union H2 { f16x2 v; uint32 u; };

__device__ __forceinline__ int wave_incl_scan(int x) {
  int lane = threadIdx.x & 63;
#pragma unroll
  for (int off = 1; off < 64; off <<= 1) {
    int t = __shfl_up(x, off, 64);
    if (lane >= off) x += t;
  }
  return x;
}

// single-block chunked exclusive scan of deg[0..n) -> rp; rp[n]=Etot. 1024 threads.
__global__ __launch_bounds__(1024) void k_scan1(const int* __restrict__ deg, int* __restrict__ rp,
                                                int n, int Etot) {
  __shared__ int wpart[16];
  __shared__ int sbase;
  int tid = threadIdx.x, lane = tid & 63, wid = tid >> 6;
  if (tid == 0) sbase = 0;
  __syncthreads();
  for (int c0 = 0; c0 < n; c0 += 4096) {
    int i0 = c0 + tid * 4;
    int v0 = 0, v1 = 0, v2 = 0, v3 = 0;
    if (i0 + 3 < n) {
      int4 t = *(const int4*)(deg + i0);
      v0 = t.x; v1 = t.y; v2 = t.z; v3 = t.w;
    } else {
      if (i0 < n) v0 = deg[i0];
      if (i0 + 1 < n) v1 = deg[i0 + 1];
      if (i0 + 2 < n) v2 = deg[i0 + 2];
      if (i0 + 3 < n) v3 = deg[i0 + 3];
    }
    int ts = v0 + v1 + v2 + v3;
    int incl = wave_incl_scan(ts);
    if (lane == 63) wpart[wid] = incl;
    __syncthreads();
    if (wid == 0 && lane < 16) {
      int xv = wpart[lane];
#pragma unroll
      for (int off = 1; off < 16; off <<= 1) {
        int t = __shfl_up(xv, off, 64);
        if (lane >= off) xv += t;
      }
      wpart[lane] = xv;  // inclusive over wave partials
    }
    __syncthreads();
    int tot = wpart[15];  // read into register BEFORE the next chunk overwrites wpart
    int base = sbase + (wid ? wpart[wid - 1] : 0);
    int excl = base + incl - ts;
    if (i0 + 3 < n) {
      int4 o; o.x = excl; o.y = excl + v0; o.z = excl + v0 + v1; o.w = excl + v0 + v1 + v2;
      *(int4*)(rp + i0) = o;
    } else {
      if (i0 < n) rp[i0] = excl;
      if (i0 + 1 < n) rp[i0 + 1] = excl + v0;
      if (i0 + 2 < n) rp[i0 + 2] = excl + v0 + v1;
      if (i0 + 3 < n) rp[i0 + 3] = excl + v0 + v1 + v2;
    }
    __syncthreads();  // all reads of sbase/wpart done before tid0 mutates sbase
    if (tid == 0) sbase += tot;
  }
  if (tid == 0) rp[n] = Etot;
}

// ---- merged: layer-1 weight fold (blocks [0,770)) + degree count (blocks [770,..)) ----
__global__ __launch_bounds__(256) void k_predeg(const float* __restrict__ T1w, const float* __restrict__ T1b,
                                                const float* __restrict__ T2w, const float* __restrict__ T2b,
                                                const float* __restrict__ G1, const float* __restrict__ G2,
                                                __half* __restrict__ Bf, float* __restrict__ cvec,
                                                const int* __restrict__ dst, int* __restrict__ deg, int E) {
  int bb = blockIdx.x;
  int j = threadIdx.x;
  if (bb >= 770) {  // degree-count branch (block-uniform)
    int e = (bb - 770) * 256 + j;
    if (e < E) atomicAdd(&deg[dst[e]], 1);
    return;
  }
  const float* G = (bb < 385) ? G1 : G2;
  int off = (bb < 385) ? 0 : 256;
  int r = (bb < 385) ? bb : bb - 385;  // 0..384: K index (384 rows) + 1 bias row
  float acc = 0.f;
  if (r < 256) {
    for (int m = 0; m < 128; m++) acc += T1w[r * 128 + m] * G[m * 256 + j];
  } else if (r < 384) {
    int rr = r - 256;
    for (int m = 0; m < 128; m++) acc += T2w[rr * 128 + m] * G[(128 + m) * 256 + j];
  } else {
    for (int m = 0; m < 128; m++) acc += T1b[m] * G[m * 256 + j] + T2b[m] * G[(128 + m) * 256 + j];
    cvec[off + j] = acc;
    return;
  }
  int k = r, colabs = off + j;
  int kt = k >> 5, lq = (k >> 3) & 3, j8 = k & 7;
  int cb = colabs >> 7, colr = colabs & 127, ni = colr >> 4, lr = colr & 15;
  size_t idx = ((size_t)(((cb * 12 + kt) * 8 + ni) * 4 + lq) * 16 + lr) * 8 + j8;
  Bf[idx] = __float2half(acc);
}

// async global->LDS, 16B per lane; LDS dest is wave-uniform base + lane*16
#define GLL(GP, LP)                                                     \
  __builtin_amdgcn_global_load_lds(                                     \
      (const __attribute__((address_space(1))) void*)(GP),              \
      (__attribute__((address_space(3))) void*)(LP), 16, 0, 0)

// ---- merged: fp16 MFMA GEMM (blocks [0,GB)) + CSR fill (blocks [GB,..)) ----
// GEMM (proven v9/v12): interleaved fp16 out; B via 3 LDS slots + GLL depth-2 + counted
// vmcnt; dense A staging through XOR-swizzled LDS; raw barriers with lgkmcnt drain.
__global__ __launch_bounds__(256, 4) void k_gemmfill(const float* __restrict__ sm, const float* __restrict__ sp,
                                                     const u16* __restrict__ Bf, const float* __restrict__ cvec,
                                                     __half* __restrict__ fs, __half* __restrict__ fd, int N,
                                                     int GB, const int* __restrict__ src,
                                                     const int* __restrict__ dst, const int* __restrict__ rp,
                                                     int* __restrict__ cnt, int* __restrict__ csr_src, int E) {
  __shared__ u16 BFl[3 * 4096];  // 24 KB: B fragments, identity-mapped GLL
  __shared__ u16 AFl[2 * 4096];  // 16 KB: A fp16 [slot][128 rows][32 halves], XOR-swizzled
  int tid = threadIdx.x;
  if (blockIdx.x >= GB) {  // CSR-fill branch (block-uniform; no barriers touched)
    int e = (blockIdx.x - GB) * 256 + tid;
    if (e < E) {
      int d = dst[e];
      int p = rp[d] + atomicAdd(&cnt[d], 1);
      csr_src[p] = src[e];
    }
    return;
  }
  int w = tid >> 6, l = tid & 63;
  int lr = l & 15, lq = l >> 4;
  int L = blockIdx.x;
  int x = L & 7, m = L >> 3;
  int cb = m & 3;
  int rb = x + 8 * (m >> 2);
  int col0 = cb * 128, row0 = rb * 128;
  if (row0 >= N) return;  // padded row-panels: whole block exits uniformly (before barriers)

  int o_sm[4], o_sp[4], woff[4];
#pragma unroll
  for (int i = 0; i < 4; i++) {
    int idx = i * 256 + tid;
    int r = idx >> 3, c8 = idx & 7;
    int rg = row0 + r; if (rg >= N) rg = N - 1;
    o_sm[i] = rg * 256 + c8 * 4;  // float units
    o_sp[i] = rg * 128 + c8 * 4;
    woff[i] = r * 32 + ((c8 * 4) ^ ((r & 6) << 2));  // halfword units, XOR-swizzled
  }
  int r0l = w * 32 + lr, r1l = r0l + 16;
  int ra0 = r0l * 32 + ((lq * 8) ^ ((r0l & 6) << 2));
  int ra1 = r1l * 32 + ((lq * 8) ^ ((r1l & 6) << 2));

  f32x4 acc[2][8];
#pragma unroll
  for (int mt = 0; mt < 2; mt++)
#pragma unroll
    for (int ni = 0; ni < 8; ni++) acc[mt][ni] = (f32x4){0.f, 0.f, 0.f, 0.f};

#define STAGE_B(S, BUF)                                                 \
  {                                                                     \
    size_t g0 = (size_t)(cb * 12 + (S)) * 4096;                         \
    _Pragma("unroll") for (int i = 0; i < 2; i++) {                     \
      int c = i * 256 + tid;                                            \
      int lb = (BUF)*4096 + (i * 4 + w) * 512;                          \
      GLL(Bf + g0 + (size_t)c * 8, &BFl[lb]);                           \
    }                                                                   \
  }

#define ALOAD(S)                                                        \
  {                                                                     \
    _Pragma("unroll") for (int i = 0; i < 4; i++) {                     \
      const float* g = ((S) < 8) ? (sm + o_sm[i] + (S)*32) : (sp + o_sp[i] + ((S)-8) * 32); \
      D[i] = *(const float4*)g;                                         \
    }                                                                   \
  }

#define AWRITE(SLOT)                                                    \
  {                                                                     \
    _Pragma("unroll") for (int i = 0; i < 4; i++) {                     \
      f16x4 h;                                                          \
      h[0] = (_Float16)D[i].x; h[1] = (_Float16)D[i].y;                 \
      h[2] = (_Float16)D[i].z; h[3] = (_Float16)D[i].w;                 \
      *(f16x4*)&AFl[(SLOT)*4096 + woff[i]] = h;                         \
    }                                                                   \
  }

  float4 D[4];
  ALOAD(0);         // [A0:4]
  STAGE_B(0, 0);    // [G0:2]
  STAGE_B(1, 1);    // [G1:2] -> outstanding 8
  asm volatile("s_waitcnt vmcnt(4)" ::: "memory");  // A0 done (G0,G1 in flight)
  AWRITE(0);
  asm volatile("s_waitcnt vmcnt(2)" ::: "memory");  // G0 done (G1 in flight)
  asm volatile("s_waitcnt lgkmcnt(0)" ::: "memory");  // drain AWRITE before barrier
  __builtin_amdgcn_sched_barrier(0);
  __builtin_amdgcn_s_barrier();

#pragma unroll
  for (int st = 0; st < 12; st++) {
    const int cu = st & 1, nx = cu ^ 1, bs = st % 3;
    if (st < 11) ALOAD(st + 1);                  // A(st+1): covered by this stage's compute
    if (st < 10) STAGE_B(st + 2, (st + 2) % 3);  // G(st+2): in flight across next barrier
    f16x8 a0 = *(const f16x8*)&AFl[cu * 4096 + ra0];
    f16x8 a1 = *(const f16x8*)&AFl[cu * 4096 + ra1];
#pragma unroll
    for (int ni = 0; ni < 8; ni++) {
      f16x8 bf = *(const f16x8*)&BFl[bs * 4096 + (ni * 64 + l) * 8];  // lane-contiguous
      acc[0][ni] = __builtin_amdgcn_mfma_f32_16x16x32_f16(a0, bf, acc[0][ni], 0, 0, 0);
      acc[1][ni] = __builtin_amdgcn_mfma_f32_16x16x32_f16(a1, bf, acc[1][ni], 0, 0, 0);
    }
    if (st < 10) {
      asm volatile("s_waitcnt vmcnt(2)" ::: "memory");
    } else if (st == 10) {
      asm volatile("s_waitcnt vmcnt(0)" ::: "memory");
    }
    if (st < 11) {
      AWRITE(nx);
      asm volatile("s_waitcnt lgkmcnt(0)" ::: "memory");  // drain ds_writes before barrier
      __builtin_amdgcn_sched_barrier(0);
      __builtin_amdgcn_s_barrier();
    }
  }

  // epilogue: C row = lq*4 + reg, col = lane&15 per 16x16 tile; store fp16 interleaved
#pragma unroll
  for (int mt = 0; mt < 2; mt++) {
    int rbr = row0 + w * 32 + mt * 16 + lq * 4;
#pragma unroll
    for (int ni = 0; ni < 8; ni++) {
      int c = col0 + ni * 16 + lr;
      float cv = cvec[c];
      __half* op = fs; int cc = c;
      if (c >= 256) { op = fd; cc = c - 256; }
#pragma unroll
      for (int r = 0; r < 4; r++) {
        int rr = rbr + r;
        if (rr < N) op[(size_t)rr * 256 + cc] = __float2half(acc[mt][ni][r] + cv);
      }
    }
  }
#undef STAGE_B
#undef ALOAD
#undef AWRITE
}

// ---- layer-2 feature GEMM: fs/fd[N,256] = h[N,32] @ W[32,256] ----
__global__ __launch_bounds__(256) void k_feat2(const float* __restrict__ h, const float* __restrict__ Ws,
                                               const float* __restrict__ Wd, __half* __restrict__ fs,
                                               __half* __restrict__ fd, int N) {
  int j = threadIdx.x;
  int n0 = blockIdx.x * 32;
  float ws[32], wd[32];
#pragma unroll
  for (int k = 0; k < 32; k++) {
    ws[k] = Ws[k * 256 + j];
    wd[k] = Wd[k * 256 + j];
  }
  int nend = n0 + 32; if (nend > N) nend = N;
#pragma unroll 2
  for (int n = n0; n < nend; n++) {
    const float4* hr4 = (const float4*)(h + (size_t)n * 32);  // wave-uniform -> s_load_dwordx4
    float as = 0.f, ad = 0.f;
#pragma unroll
    for (int kk = 0; kk < 8; kk++) {
      float4 t = hr4[kk];
      as += t.x * ws[4 * kk] + t.y * ws[4 * kk + 1] + t.z * ws[4 * kk + 2] + t.w * ws[4 * kk + 3];
      ad += t.x * wd[4 * kk] + t.y * wd[4 * kk + 1] + t.z * wd[4 * kk + 2] + t.w * wd[4 * kk + 3];
    }
    fs[(size_t)n * 256 + j] = __float2half(as);
    fd[(size_t)n * 256 + j] = __float2half(ad);
  }
}

// ---- fused edge pass v14: half-wave edge pairing + DEPTH-3 pair pipeline ----
// Lane reads uint4 (8 feats); 32 lanes cover a 512B row; two wave halves process two edges
// at once. Three pair-gathers kept in flight (x0/x1/x2 rotation: issue pair q, compute
// pair q-3) -> 3x memory parallelism per wave vs depth-1. pair1 call order unchanged ->
// bit-identical numerics. Softmax reduce = 2 shfl; odd-degree tail: half-B weight 0.
template <int FINAL>
__global__ __launch_bounds__(256) void k_edge(const uint4* __restrict__ fs4, const uint4* __restrict__ fd4,
                                              const int* __restrict__ csr_src, const int* __restrict__ rp,
                                              const float* __restrict__ attn, const float* __restrict__ bias,
                                              float* __restrict__ out, int N) {
  int n = blockIdx.x * 4 + (threadIdx.x >> 6);
  if (n >= N) return;
  int lane = threadIdx.x & 63;
  int lh = lane & 31;  // position within half; lane holds feats 8*lh .. 8*lh+7
  float4 a0 = ((const float4*)attn)[lh * 2];
  float4 a1 = ((const float4*)attn)[lh * 2 + 1];
  H2 AV01, AV23, AV45, AV67;
  AV01.v = (f16x2){(_Float16)a0.x, (_Float16)a0.y};
  AV23.v = (f16x2){(_Float16)a0.z, (_Float16)a0.w};
  AV45.v = (f16x2){(_Float16)a1.x, (_Float16)a1.y};
  AV67.v = (f16x2){(_Float16)a1.z, (_Float16)a1.w};
  const f16x2 c02 = {(_Float16)0.2f, (_Float16)0.2f};
  uint4 yu = fd4[(size_t)n * 32 + lh];
  H2 Y01, Y23, Y45, Y67;
  Y01.u = yu.x; Y23.u = yu.y; Y45.u = yu.z; Y67.u = yu.w;
  int beg = rp[n], end = rp[n + 1];
  float den = 0.f;
  float acc[8] = {0.f, 0.f, 0.f, 0.f, 0.f, 0.f, 0.f, 0.f};

  auto pair1 = [&](uint4 xu, bool tail) {
    H2 Xa, Xb, Xc, Xd;
    Xa.u = xu.x; Xb.u = xu.y; Xc.u = xu.z; Xd.u = xu.w;
    f16x2 e0 = Xa.v + Y01.v, e1 = Xb.v + Y23.v, e2 = Xc.v + Y45.v, e3 = Xd.v + Y67.v;
    f16x2 t0 = __builtin_elementwise_max(e0, e0 * c02);
    f16x2 t1 = __builtin_elementwise_max(e1, e1 * c02);
    f16x2 t2 = __builtin_elementwise_max(e2, e2 * c02);
    f16x2 t3 = __builtin_elementwise_max(e3, e3 * c02);
    float p = __builtin_amdgcn_fdot2(t0, AV01.v, 0.f, false);
    p = __builtin_amdgcn_fdot2(t1, AV23.v, p, false);
    p = __builtin_amdgcn_fdot2(t2, AV45.v, p, false);
    p = __builtin_amdgcn_fdot2(t3, AV67.v, p, false);
    p += __shfl_xor(p, 1, 64);  // 4-lane head group reduce
    p += __shfl_xor(p, 2, 64);
    float wgt = __expf(p);  // scores bounded: exp-safe without max shift
    if (tail && lane >= 32) wgt = 0.f;  // odd-degree tail: half B invalid
    den += wgt;
    acc[0] += wgt * (float)Xa.v.x; acc[1] += wgt * (float)Xa.v.y;
    acc[2] += wgt * (float)Xb.v.x; acc[3] += wgt * (float)Xb.v.y;
    acc[4] += wgt * (float)Xc.v.x; acc[5] += wgt * (float)Xc.v.y;
    acc[6] += wgt * (float)Xd.v.x; acc[7] += wgt * (float)Xd.v.y;
  };

  int e = beg;
  int np = (end - beg) >> 1;
  if (np > 0) {
    auto gpair = [&](int q) -> uint4 {
      int eb = e + 2 * q;
      int tA = csr_src[eb], tB = csr_src[eb + 1];  // wave-uniform scalar loads
      int t = (lane < 32) ? tA : tB;
      return fs4[(size_t)t * 32 + lh];
    };
    uint4 x0 = gpair(0);
    uint4 x1, x2;
    if (np > 1) x1 = gpair(1);
    if (np > 2) x2 = gpair(2);
    for (int q = 3; q < np; q++) {
      uint4 xf = gpair(q);     // pair q in flight (3 outstanding while computing q-3)
      pair1(x0, false);
      x0 = x1; x1 = x2; x2 = xf;
    }
    pair1(x0, false);
    if (np > 1) pair1(x1, false);
    if (np > 2) pair1(x2, false);
    e += 2 * np;
  }
  if (e < end) {  // odd-degree tail
    int sA = csr_src[e];
    uint4 xu = fs4[(size_t)sA * 32 + lh];
    pair1(xu, true);
  }

  // cross-half combine: halves A/B accumulated disjoint edge subsets of the same dst
  den += __shfl_xor(den, 32, 64);
#pragma unroll
  for (int j = 0; j < 8; j++) acc[j] += __shfl_xor(acc[j], 32, 64);
  float invd = 1.f / den;
  float4 b0 = ((const float4*)bias)[lh * 2];
  float4 b1 = ((const float4*)bias)[lh * 2 + 1];
  float bj[8] = {b0.x, b0.y, b0.z, b0.w, b1.x, b1.y, b1.z, b1.w};
#pragma unroll
  for (int j = 0; j < 8; j++) {
    float v = acc[j] * invd + bj[j];
    if (!FINAL) v = v > 0.f ? v : expm1f(v);
    acc[j] = v;
  }
  // head-mean: feat f = lh*8+j; head h = lh>>2; d = (lh&3)*8+j -> reduce lanes stride-4
#pragma unroll
  for (int mask = 4; mask <= 16; mask <<= 1)
#pragma unroll
    for (int j = 0; j < 8; j++) acc[j] += __shfl_xor(acc[j], mask, 64);
  if (lane < 4) {  // lane p holds d = p*8 .. p*8+7
    float4 o0 = {acc[0] * 0.125f, acc[1] * 0.125f, acc[2] * 0.125f, acc[3] * 0.125f};
    float4 o1 = {acc[4] * 0.125f, acc[5] * 0.125f, acc[6] * 0.125f, acc[7] * 0.125f};
    ((float4*)out)[(size_t)n * 8 + lane * 2] = o0;
    ((float4*)out)[(size_t)n * 8 + lane * 2 + 1] = o1;
  }
}

extern "C" void kernel_launch(void* const* d_in, const int* in_sizes, int n_in,
                              void* d_out, int out_size, void* d_ws, size_t ws_size,
                              hipStream_t stream) {
  const float* sm  = (const float*)d_in[0];
  const float* sp  = (const float*)d_in[1];
  const int*   src = (const int*)d_in[2];
  const int*   dst = (const int*)d_in[3];
  const float* T1w = (const float*)d_in[4];
  const float* T1b = (const float*)d_in[5];
  const float* T2w = (const float*)d_in[6];
  const float* T2b = (const float*)d_in[7];
  const float* g1sw = (const float*)d_in[8];
  const float* g1dw = (const float*)d_in[9];
  const float* g1a  = (const float*)d_in[10];
  const float* g1b  = (const float*)d_in[11];
  const float* g2sw = (const float*)d_in[12];
  const float* g2dw = (const float*)d_in[13];
  const float* g2a  = (const float*)d_in[14];
  const float* g2b  = (const float*)d_in[15];
  const int N = in_sizes[1] / 128;  // sp_feats is [N,128]
  const int E = in_sizes[2];
  float* out = (float*)d_out;

  size_t off = 0;
  char* wsb = (char*)d_ws;
  auto alloc = [&](size_t bytes) -> void* {
    void* p = wsb + off;
    off += (bytes + 255) & ~(size_t)255;
    return p;
  };
  __half* Bf  = (__half*)alloc((size_t)512 * 384 * 2);
  float* cvec  = (float*)alloc(512 * 4);
  int* deg     = (int*)alloc((size_t)N * 4);
  int* cnt     = (int*)alloc((size_t)N * 4);
  int* row_ptr = (int*)alloc((size_t)(N + 1) * 4);
  int* csr_src = (int*)alloc((size_t)E * 4);
  __half* fs   = (__half*)alloc((size_t)N * 256 * 2);
  __half* fd   = (__half*)alloc((size_t)N * 256 * 2);
  float* hmid  = (float*)alloc((size_t)N * 32 * 4);
  (void)ws_size; (void)n_in; (void)out_size;

  (void)hipMemsetAsync(deg, 0, (size_t)N * 4, stream);
  (void)hipMemsetAsync(cnt, 0, (size_t)N * 4, stream);

  int DB = (E + 255) / 256;  // edge blocks

  // merged: precomb (770 blocks) || degree count (DB blocks)
  k_predeg<<<770 + DB, 256, 0, stream>>>(T1w, T1b, T2w, T2b, g1sw, g1dw, Bf, cvec, dst, deg, E);
  k_scan1<<<1, 1024, 0, stream>>>(deg, row_ptr, N, E);

  // merged: layer-1 GEMM (GB blocks, XCD-swizzled; GB % 8 == 0) || CSR fill (DB blocks)
  int rbs = (N + 127) / 128;
  int rbp = (rbs + 7) & ~7;
  int GB = rbp * 4;
  k_gemmfill<<<GB + DB, 256, 0, stream>>>(sm, sp, (const u16*)Bf, cvec, fs, fd, N,
                                          GB, src, dst, row_ptr, cnt, csr_src, E);
  k_edge<0><<<(N + 3) / 4, 256, 0, stream>>>((const uint4*)fs, (const uint4*)fd, csr_src, row_ptr, g1a, g1b, hmid, N);

  // layer 2
  k_feat2<<<(N + 31) / 32, 256, 0, stream>>>(hmid, g2sw, g2dw, fs, fd, N);
  k_edge<1><<<(N + 3) / 4, 256, 0, stream>>>((const uint4*)fs, (const uint4*)fd, csr_src, row_ptr, g2a, g2b, out, N);
}

// Round 15
// 428.250 us; speedup vs baseline: 1.0688x; 1.0383x over previous
//
#include <hip/hip_runtime.h>
#include <hip/hip_fp16.h>

// N=50000 nodes, E=850000 edges, H=8 heads, D=32, H*D=256, IN=128, SM=256, SP=128

typedef unsigned int uint32;
typedef unsigned short u16;
typedef float f32x4 __attribute__((ext_vector_type(4)));
typedef _Float16 f16x2 __attribute__((ext_vector_type(2)));
typedef _Float16 f16x4 __attribute__((ext_vector_type(4)));
typedef _Float16 f16x8 __attribute__((ext_vector_type(8)));

union H2 { f16x2 v; uint32 u; };

__device__ __forceinline__ int wave_incl_scan(int x) {
  int lane = threadIdx.x & 63;
#pragma unroll
  for (int off = 1; off < 64; off <<= 1) {
    int t = __shfl_up(x, off, 64);
    if (lane >= off) x += t;
  }
  return x;
}

// single-block chunked exclusive scan of deg[0..n) -> rp; rp[n]=Etot. 1024 threads.
__global__ __launch_bounds__(1024) void k_scan1(const int* __restrict__ deg, int* __restrict__ rp,
                                                int n, int Etot) {
  __shared__ int wpart[16];
  __shared__ int sbase;
  int tid = threadIdx.x, lane = tid & 63, wid = tid >> 6;
  if (tid == 0) sbase = 0;
  __syncthreads();
  for (int c0 = 0; c0 < n; c0 += 4096) {
    int i0 = c0 + tid * 4;
    int v0 = 0, v1 = 0, v2 = 0, v3 = 0;
    if (i0 + 3 < n) {
      int4 t = *(const int4*)(deg + i0);
      v0 = t.x; v1 = t.y; v2 = t.z; v3 = t.w;
    } else {
      if (i0 < n) v0 = deg[i0];
      if (i0 + 1 < n) v1 = deg[i0 + 1];
      if (i0 + 2 < n) v2 = deg[i0 + 2];
      if (i0 + 3 < n) v3 = deg[i0 + 3];
    }
    int ts = v0 + v1 + v2 + v3;
    int incl = wave_incl_scan(ts);
    if (lane == 63) wpart[wid] = incl;
    __syncthreads();
    if (wid == 0 && lane < 16) {
      int xv = wpart[lane];
#pragma unroll
      for (int off = 1; off < 16; off <<= 1) {
        int t = __shfl_up(xv, off, 64);
        if (lane >= off) xv += t;
      }
      wpart[lane] = xv;  // inclusive over wave partials
    }
    __syncthreads();
    int tot = wpart[15];  // read into register BEFORE the next chunk overwrites wpart
    int base = sbase + (wid ? wpart[wid - 1] : 0);
    int excl = base + incl - ts;
    if (i0 + 3 < n) {
      int4 o; o.x = excl; o.y = excl + v0; o.z = excl + v0 + v1; o.w = excl + v0 + v1 + v2;
      *(int4*)(rp + i0) = o;
    } else {
      if (i0 < n) rp[i0] = excl;
      if (i0 + 1 < n) rp[i0 + 1] = excl + v0;
      if (i0 + 2 < n) rp[i0 + 2] = excl + v0 + v1;
      if (i0 + 3 < n) rp[i0 + 3] = excl + v0 + v1 + v2;
    }
    __syncthreads();  // all reads of sbase/wpart done before tid0 mutates sbase
    if (tid == 0) sbase += tot;
  }
  if (tid == 0) rp[n] = Etot;
}

// ---- merged: layer-1 weight fold (blocks [0,770)) + degree count (blocks [770,..)) ----
__global__ __launch_bounds__(256) void k_predeg(const float* __restrict__ T1w, const float* __restrict__ T1b,
                                                const float* __restrict__ T2w, const float* __restrict__ T2b,
                                                const float* __restrict__ G1, const float* __restrict__ G2,
                                                __half* __restrict__ Bf, float* __restrict__ cvec,
                                                const int* __restrict__ dst, int* __restrict__ deg, int E) {
  int bb = blockIdx.x;
  int j = threadIdx.x;
  if (bb >= 770) {  // degree-count branch (block-uniform)
    int e = (bb - 770) * 256 + j;
    if (e < E) atomicAdd(&deg[dst[e]], 1);
    return;
  }
  const float* G = (bb < 385) ? G1 : G2;
  int off = (bb < 385) ? 0 : 256;
  int r = (bb < 385) ? bb : bb - 385;  // 0..384: K index (384 rows) + 1 bias row
  float acc = 0.f;
  if (r < 256) {
    for (int m = 0; m < 128; m++) acc += T1w[r * 128 + m] * G[m * 256 + j];
  } else if (r < 384) {
    int rr = r - 256;
    for (int m = 0; m < 128; m++) acc += T2w[rr * 128 + m] * G[(128 + m) * 256 + j];
  } else {
    for (int m = 0; m < 128; m++) acc += T1b[m] * G[m * 256 + j] + T2b[m] * G[(128 + m) * 256 + j];
    cvec[off + j] = acc;
    return;
  }
  int k = r, colabs = off + j;
  int kt = k >> 5, lq = (k >> 3) & 3, j8 = k & 7;
  int cb = colabs >> 7, colr = colabs & 127, ni = colr >> 4, lr = colr & 15;
  size_t idx = ((size_t)(((cb * 12 + kt) * 8 + ni) * 4 + lq) * 16 + lr) * 8 + j8;
  Bf[idx] = __float2half(acc);
}

// async global->LDS, 16B per lane; LDS dest is wave-uniform base + lane*16
#define GLL(GP, LP)                                                     \
  __builtin_amdgcn_global_load_lds(                                     \
      (const __attribute__((address_space(1))) void*)(GP),              \
      (__attribute__((address_space(3))) void*)(LP), 16, 0, 0)

// ---- merged: fp16 MFMA GEMM (blocks [0,GB)) + CSR fill (blocks [GB,..)) ----
// GEMM (proven v9/v12): interleaved fp16 out; B via 3 LDS slots + GLL depth-2 + counted
// vmcnt; dense A staging through XOR-swizzled LDS; raw barriers with lgkmcnt drain.
__global__ __launch_bounds__(256, 4) void k_gemmfill(const float* __restrict__ sm, const float* __restrict__ sp,
                                                     const u16* __restrict__ Bf, const float* __restrict__ cvec,
                                                     __half* __restrict__ fs, __half* __restrict__ fd, int N,
                                                     int GB, const int* __restrict__ src,
                                                     const int* __restrict__ dst, const int* __restrict__ rp,
                                                     int* __restrict__ cnt, int* __restrict__ csr_src, int E) {
  __shared__ u16 BFl[3 * 4096];  // 24 KB: B fragments, identity-mapped GLL
  __shared__ u16 AFl[2 * 4096];  // 16 KB: A fp16 [slot][128 rows][32 halves], XOR-swizzled
  int tid = threadIdx.x;
  if (blockIdx.x >= GB) {  // CSR-fill branch (block-uniform; no barriers touched)
    int e = (blockIdx.x - GB) * 256 + tid;
    if (e < E) {
      int d = dst[e];
      int p = rp[d] + atomicAdd(&cnt[d], 1);
      csr_src[p] = src[e];
    }
    return;
  }
  int w = tid >> 6, l = tid & 63;
  int lr = l & 15, lq = l >> 4;
  int L = blockIdx.x;
  int x = L & 7, m = L >> 3;
  int cb = m & 3;
  int rb = x + 8 * (m >> 2);
  int col0 = cb * 128, row0 = rb * 128;
  if (row0 >= N) return;  // padded row-panels: whole block exits uniformly (before barriers)

  int o_sm[4], o_sp[4], woff[4];
#pragma unroll
  for (int i = 0; i < 4; i++) {
    int idx = i * 256 + tid;
    int r = idx >> 3, c8 = idx & 7;
    int rg = row0 + r; if (rg >= N) rg = N - 1;
    o_sm[i] = rg * 256 + c8 * 4;  // float units
    o_sp[i] = rg * 128 + c8 * 4;
    woff[i] = r * 32 + ((c8 * 4) ^ ((r & 6) << 2));  // halfword units, XOR-swizzled
  }
  int r0l = w * 32 + lr, r1l = r0l + 16;
  int ra0 = r0l * 32 + ((lq * 8) ^ ((r0l & 6) << 2));
  int ra1 = r1l * 32 + ((lq * 8) ^ ((r1l & 6) << 2));

  f32x4 acc[2][8];
#pragma unroll
  for (int mt = 0; mt < 2; mt++)
#pragma unroll
    for (int ni = 0; ni < 8; ni++) acc[mt][ni] = (f32x4){0.f, 0.f, 0.f, 0.f};

#define STAGE_B(S, BUF)                                                 \
  {                                                                     \
    size_t g0 = (size_t)(cb * 12 + (S)) * 4096;                         \
    _Pragma("unroll") for (int i = 0; i < 2; i++) {                     \
      int c = i * 256 + tid;                                            \
      int lb = (BUF)*4096 + (i * 4 + w) * 512;                          \
      GLL(Bf + g0 + (size_t)c * 8, &BFl[lb]);                           \
    }                                                                   \
  }

#define ALOAD(S)                                                        \
  {                                                                     \
    _Pragma("unroll") for (int i = 0; i < 4; i++) {                     \
      const float* g = ((S) < 8) ? (sm + o_sm[i] + (S)*32) : (sp + o_sp[i] + ((S)-8) * 32); \
      D[i] = *(const float4*)g;                                         \
    }                                                                   \
  }

#define AWRITE(SLOT)                                                    \
  {                                                                     \
    _Pragma("unroll") for (int i = 0; i < 4; i++) {                     \
      f16x4 h;                                                          \
      h[0] = (_Float16)D[i].x; h[1] = (_Float16)D[i].y;                 \
      h[2] = (_Float16)D[i].z; h[3] = (_Float16)D[i].w;                 \
      *(f16x4*)&AFl[(SLOT)*4096 + woff[i]] = h;                         \
    }                                                                   \
  }

  float4 D[4];
  ALOAD(0);         // [A0:4]
  STAGE_B(0, 0);    // [G0:2]
  STAGE_B(1, 1);    // [G1:2] -> outstanding 8
  asm volatile("s_waitcnt vmcnt(4)" ::: "memory");  // A0 done (G0,G1 in flight)
  AWRITE(0);
  asm volatile("s_waitcnt vmcnt(2)" ::: "memory");  // G0 done (G1 in flight)
  asm volatile("s_waitcnt lgkmcnt(0)" ::: "memory");  // drain AWRITE before barrier
  __builtin_amdgcn_sched_barrier(0);
  __builtin_amdgcn_s_barrier();

#pragma unroll
  for (int st = 0; st < 12; st++) {
    const int cu = st & 1, nx = cu ^ 1, bs = st % 3;
    if (st < 11) ALOAD(st + 1);                  // A(st+1): covered by this stage's compute
    if (st < 10) STAGE_B(st + 2, (st + 2) % 3);  // G(st+2): in flight across next barrier
    f16x8 a0 = *(const f16x8*)&AFl[cu * 4096 + ra0];
    f16x8 a1 = *(const f16x8*)&AFl[cu * 4096 + ra1];
#pragma unroll
    for (int ni = 0; ni < 8; ni++) {
      f16x8 bf = *(const f16x8*)&BFl[bs * 4096 + (ni * 64 + l) * 8];  // lane-contiguous
      acc[0][ni] = __builtin_amdgcn_mfma_f32_16x16x32_f16(a0, bf, acc[0][ni], 0, 0, 0);
      acc[1][ni] = __builtin_amdgcn_mfma_f32_16x16x32_f16(a1, bf, acc[1][ni], 0, 0, 0);
    }
    if (st < 10) {
      asm volatile("s_waitcnt vmcnt(2)" ::: "memory");
    } else if (st == 10) {
      asm volatile("s_waitcnt vmcnt(0)" ::: "memory");
    }
    if (st < 11) {
      AWRITE(nx);
      asm volatile("s_waitcnt lgkmcnt(0)" ::: "memory");  // drain ds_writes before barrier
      __builtin_amdgcn_sched_barrier(0);
      __builtin_amdgcn_s_barrier();
    }
  }

  // epilogue: C row = lq*4 + reg, col = lane&15 per 16x16 tile; store fp16 interleaved
#pragma unroll
  for (int mt = 0; mt < 2; mt++) {
    int rbr = row0 + w * 32 + mt * 16 + lq * 4;
#pragma unroll
    for (int ni = 0; ni < 8; ni++) {
      int c = col0 + ni * 16 + lr;
      float cv = cvec[c];
      __half* op = fs; int cc = c;
      if (c >= 256) { op = fd; cc = c - 256; }
#pragma unroll
      for (int r = 0; r < 4; r++) {
        int rr = rbr + r;
        if (rr < N) op[(size_t)rr * 256 + cc] = __float2half(acc[mt][ni][r] + cv);
      }
    }
  }
#undef STAGE_B
#undef ALOAD
#undef AWRITE
}

// ---- layer-2 feature GEMM: fs/fd[N,256] = h[N,32] @ W[32,256] ----
__global__ __launch_bounds__(256) void k_feat2(const float* __restrict__ h, const float* __restrict__ Ws,
                                               const float* __restrict__ Wd, __half* __restrict__ fs,
                                               __half* __restrict__ fd, int N) {
  int j = threadIdx.x;
  int n0 = blockIdx.x * 32;
  float ws[32], wd[32];
#pragma unroll
  for (int k = 0; k < 32; k++) {
    ws[k] = Ws[k * 256 + j];
    wd[k] = Wd[k * 256 + j];
  }
  int nend = n0 + 32; if (nend > N) nend = N;
#pragma unroll 2
  for (int n = n0; n < nend; n++) {
    const float4* hr4 = (const float4*)(h + (size_t)n * 32);  // wave-uniform -> s_load_dwordx4
    float as = 0.f, ad = 0.f;
#pragma unroll
    for (int kk = 0; kk < 8; kk++) {
      float4 t = hr4[kk];
      as += t.x * ws[4 * kk] + t.y * ws[4 * kk + 1] + t.z * ws[4 * kk + 2] + t.w * ws[4 * kk + 3];
      ad += t.x * wd[4 * kk] + t.y * wd[4 * kk + 1] + t.z * wd[4 * kk + 2] + t.w * wd[4 * kk + 3];
    }
    fs[(size_t)n * 256 + j] = __float2half(as);
    fd[(size_t)n * 256 + j] = __float2half(ad);
  }
}

// ---- fused edge pass: half-wave edge pairing (proven r6/r12; depth-1 prefetch optimal) ----
// Lane reads uint4 (8 feats); 32 lanes cover a 512B row; two wave halves process two edges
// at once; softmax reduce = 2 shfl (4-lane head groups); odd-degree tail: half-B weight 0.
template <int FINAL>
__global__ __launch_bounds__(256) void k_edge(const uint4* __restrict__ fs4, const uint4* __restrict__ fd4,
                                              const int* __restrict__ csr_src, const int* __restrict__ rp,
                                              const float* __restrict__ attn, const float* __restrict__ bias,
                                              float* __restrict__ out, int N) {
  int n = blockIdx.x * 4 + (threadIdx.x >> 6);
  if (n >= N) return;
  int lane = threadIdx.x & 63;
  int lh = lane & 31;  // position within half; lane holds feats 8*lh .. 8*lh+7
  float4 a0 = ((const float4*)attn)[lh * 2];
  float4 a1 = ((const float4*)attn)[lh * 2 + 1];
  H2 AV01, AV23, AV45, AV67;
  AV01.v = (f16x2){(_Float16)a0.x, (_Float16)a0.y};
  AV23.v = (f16x2){(_Float16)a0.z, (_Float16)a0.w};
  AV45.v = (f16x2){(_Float16)a1.x, (_Float16)a1.y};
  AV67.v = (f16x2){(_Float16)a1.z, (_Float16)a1.w};
  const f16x2 c02 = {(_Float16)0.2f, (_Float16)0.2f};
  uint4 yu = fd4[(size_t)n * 32 + lh];
  H2 Y01, Y23, Y45, Y67;
  Y01.u = yu.x; Y23.u = yu.y; Y45.u = yu.z; Y67.u = yu.w;
  int beg = rp[n], end = rp[n + 1];
  float den = 0.f;
  float acc[8] = {0.f, 0.f, 0.f, 0.f, 0.f, 0.f, 0.f, 0.f};

  auto pair1 = [&](uint4 xu, bool tail) {
    H2 Xa, Xb, Xc, Xd;
    Xa.u = xu.x; Xb.u = xu.y; Xc.u = xu.z; Xd.u = xu.w;
    f16x2 e0 = Xa.v + Y01.v, e1 = Xb.v + Y23.v, e2 = Xc.v + Y45.v, e3 = Xd.v + Y67.v;
    f16x2 t0 = __builtin_elementwise_max(e0, e0 * c02);
    f16x2 t1 = __builtin_elementwise_max(e1, e1 * c02);
    f16x2 t2 = __builtin_elementwise_max(e2, e2 * c02);
    f16x2 t3 = __builtin_elementwise_max(e3, e3 * c02);
    float p = __builtin_amdgcn_fdot2(t0, AV01.v, 0.f, false);
    p = __builtin_amdgcn_fdot2(t1, AV23.v, p, false);
    p = __builtin_amdgcn_fdot2(t2, AV45.v, p, false);
    p = __builtin_amdgcn_fdot2(t3, AV67.v, p, false);
    p += __shfl_xor(p, 1, 64);  // 4-lane head group reduce
    p += __shfl_xor(p, 2, 64);
    float wgt = __expf(p);  // scores bounded: exp-safe without max shift
    if (tail && lane >= 32) wgt = 0.f;  // odd-degree tail: half B invalid
    den += wgt;
    acc[0] += wgt * (float)Xa.v.x; acc[1] += wgt * (float)Xa.v.y;
    acc[2] += wgt * (float)Xb.v.x; acc[3] += wgt * (float)Xb.v.y;
    acc[4] += wgt * (float)Xc.v.x; acc[5] += wgt * (float)Xc.v.y;
    acc[6] += wgt * (float)Xd.v.x; acc[7] += wgt * (float)Xd.v.y;
  };

  int e = beg;
  int np = (end - beg) >> 1;
  if (np > 0) {
    int sA = csr_src[e], sB = csr_src[e + 1];  // wave-uniform scalar loads
    int s = (lane < 32) ? sA : sB;
    uint4 xcur = fs4[(size_t)s * 32 + lh];
    for (int q = 1; q < np; q++) {
      int eb = e + 2 * q;
      int tA = csr_src[eb], tB = csr_src[eb + 1];
      int t = (lane < 32) ? tA : tB;
      uint4 xnext = fs4[(size_t)t * 32 + lh];  // prefetch next pair
      pair1(xcur, false);
      xcur = xnext;
    }
    pair1(xcur, false);
    e += 2 * np;
  }
  if (e < end) {  // odd-degree tail
    int sA = csr_src[e];
    uint4 xu = fs4[(size_t)sA * 32 + lh];
    pair1(xu, true);
  }

  // cross-half combine: halves A/B accumulated disjoint edge subsets of the same dst
  den += __shfl_xor(den, 32, 64);
#pragma unroll
  for (int j = 0; j < 8; j++) acc[j] += __shfl_xor(acc[j], 32, 64);
  float invd = 1.f / den;
  float4 b0 = ((const float4*)bias)[lh * 2];
  float4 b1 = ((const float4*)bias)[lh * 2 + 1];
  float bj[8] = {b0.x, b0.y, b0.z, b0.w, b1.x, b1.y, b1.z, b1.w};
#pragma unroll
  for (int j = 0; j < 8; j++) {
    float v = acc[j] * invd + bj[j];
    if (!FINAL) v = v > 0.f ? v : expm1f(v);
    acc[j] = v;
  }
  // head-mean: feat f = lh*8+j; head h = lh>>2; d = (lh&3)*8+j -> reduce lanes stride-4
#pragma unroll
  for (int mask = 4; mask <= 16; mask <<= 1)
#pragma unroll
    for (int j = 0; j < 8; j++) acc[j] += __shfl_xor(acc[j], mask, 64);
  if (lane < 4) {  // lane p holds d = p*8 .. p*8+7
    float4 o0 = {acc[0] * 0.125f, acc[1] * 0.125f, acc[2] * 0.125f, acc[3] * 0.125f};
    float4 o1 = {acc[4] * 0.125f, acc[5] * 0.125f, acc[6] * 0.125f, acc[7] * 0.125f};
    ((float4*)out)[(size_t)n * 8 + lane * 2] = o0;
    ((float4*)out)[(size_t)n * 8 + lane * 2 + 1] = o1;
  }
}

extern "C" void kernel_launch(void* const* d_in, const int* in_sizes, int n_in,
                              void* d_out, int out_size, void* d_ws, size_t ws_size,
                              hipStream_t stream) {
  const float* sm  = (const float*)d_in[0];
  const float* sp  = (const float*)d_in[1];
  const int*   src = (const int*)d_in[2];
  const int*   dst = (const int*)d_in[3];
  const float* T1w = (const float*)d_in[4];
  const float* T1b = (const float*)d_in[5];
  const float* T2w = (const float*)d_in[6];
  const float* T2b = (const float*)d_in[7];
  const float* g1sw = (const float*)d_in[8];
  const float* g1dw = (const float*)d_in[9];
  const float* g1a  = (const float*)d_in[10];
  const float* g1b  = (const float*)d_in[11];
  const float* g2sw = (const float*)d_in[12];
  const float* g2dw = (const float*)d_in[13];
  const float* g2a  = (const float*)d_in[14];
  const float* g2b  = (const float*)d_in[15];
  const int N = in_sizes[1] / 128;  // sp_feats is [N,128]
  const int E = in_sizes[2];
  float* out = (float*)d_out;

  size_t off = 0;
  char* wsb = (char*)d_ws;
  auto alloc = [&](size_t bytes) -> void* {
    void* p = wsb + off;
    off += (bytes + 255) & ~(size_t)255;
    return p;
  };
  __half* Bf  = (__half*)alloc((size_t)512 * 384 * 2);
  float* cvec  = (float*)alloc(512 * 4);
  int* deg     = (int*)alloc((size_t)N * 4);
  int* cnt     = (int*)alloc((size_t)N * 4);
  int* row_ptr = (int*)alloc((size_t)(N + 1) * 4);
  int* csr_src = (int*)alloc((size_t)E * 4);
  __half* fs   = (__half*)alloc((size_t)N * 256 * 2);
  __half* fd   = (__half*)alloc((size_t)N * 256 * 2);
  float* hmid  = (float*)alloc((size_t)N * 32 * 4);
  (void)ws_size; (void)n_in; (void)out_size;

  (void)hipMemsetAsync(deg, 0, (size_t)N * 4, stream);
  (void)hipMemsetAsync(cnt, 0, (size_t)N * 4, stream);

  int DB = (E + 255) / 256;  // edge blocks

  // merged: precomb (770 blocks) || degree count (DB blocks)
  k_predeg<<<770 + DB, 256, 0, stream>>>(T1w, T1b, T2w, T2b, g1sw, g1dw, Bf, cvec, dst, deg, E);
  k_scan1<<<1, 1024, 0, stream>>>(deg, row_ptr, N, E);

  // merged: layer-1 GEMM (GB blocks, XCD-swizzled; GB % 8 == 0) || CSR fill (DB blocks)
  int rbs = (N + 127) / 128;
  int rbp = (rbs + 7) & ~7;
  int GB = rbp * 4;
  k_gemmfill<<<GB + DB, 256, 0, stream>>>(sm, sp, (const u16*)Bf, cvec, fs, fd, N,
                                          GB, src, dst, row_ptr, cnt, csr_src, E);
  k_edge<0><<<(N + 3) / 4, 256, 0, stream>>>((const uint4*)fs, (const uint4*)fd, csr_src, row_ptr, g1a, g1b, hmid, N);

  // layer 2
  k_feat2<<<(N + 31) / 32, 256, 0, stream>>>(hmid, g2sw, g2dw, fs, fd, N);
  k_edge<1><<<(N + 3) / 4, 256, 0, stream>>>((const uint4*)fs, (const uint4*)fd, csr_src, row_ptr, g2a, g2b, out, N);
}